// Round 1
// baseline (3373.814 us; speedup 1.0000x reference)
//
#include <hip/hip_runtime.h>
#include <math.h>

#define B 64
#define TF 64
#define TE 32
#define E_DIM 40
#define H 100
#define H2 200
#define H3 300
#define SP 256
#define EV 20000
#define ROWS (B*TF)        // 4096
#define NCOLS 456          // 200 score cols + 256 Y cols

// ---------------- setup: W_T (concat of att_W1 bottom + sp1_W enc part, transposed), v, c2 ----
__global__ __launch_bounds__(256) void k_setup(const float* att_W1, const float* sp1_W,
        const float* sp2_W, const float* sp2_b, float* W_T, float* v, float* c2) {
  int bid = blockIdx.x;
  if (bid < 182) {
    int idx = bid*256 + threadIdx.x;
    if (idx < NCOLS*H) {
      int c = idx / 100, k = idx - c*100;
      float val;
      if (c < H2) val = att_W1[(100+k)*H2 + c];
      else        val = sp1_W[(200+k)*SP + (c-200)];
      W_T[idx] = val;                       // W_T[c*100+k]
    }
  } else if (bid == 182) {
    int k = threadIdx.x;                    // 0..255
    float s = 0.f;
    for (int j = 0; j < SP; ++j) s += sp2_W[k*SP + j];
    v[k] = s * (1.f/256.f);
  } else {
    if (threadIdx.x == 0) {
      float s = 0.f;
      for (int j = 0; j < SP; ++j) s += sp2_b[j];
      *c2 = s * (1.f/256.f);
    }
  }
}

// ---------------- encoder xs = embed @ enc_W + enc_b[0] (parallel over all (b,t)) ----
__global__ __launch_bounds__(320) void k_embed(const int* enc_in, const float* femb,
        const float* enc_W, const float* enc_b, float* xs_all) {
  int row = blockIdx.x;
  int j = threadIdx.x;
  __shared__ __align__(16) float emb[E_DIM];
  int tok = enc_in[row];
  if (j < E_DIM) emb[j] = femb[tok*E_DIM + j];
  __syncthreads();
  if (j < H3) {
    float acc = enc_b[j];                   // b[0]
    #pragma unroll
    for (int k = 0; k < E_DIM; ++k) acc += emb[k]*enc_W[k*H3 + j];
    xs_all[row*H3 + j] = acc;
  }
}

// ---------------- encoder GRU recurrence: one block per batch ----
__global__ __launch_bounds__(320) void k_enc(const float* enc_U, const float* enc_b,
        const float* xs_all, float* enc_T, float* h_state) {
  int b = blockIdx.x, j = threadIdx.x;
  __shared__ __align__(16) float h[104];
  __shared__ __align__(16) float hs[304];
  if (j < H) h[j] = 0.f;
  __syncthreads();
  for (int t = 0; t < TF; ++t) {
    if (j < H3) {
      float acc = enc_b[H3 + j];            // b[1]
      const float4* h4 = (const float4*)h;
      #pragma unroll
      for (int k4 = 0; k4 < 25; ++k4) {
        float4 hv = h4[k4];
        int k = k4*4;
        acc += hv.x*enc_U[(k+0)*H3+j];
        acc += hv.y*enc_U[(k+1)*H3+j];
        acc += hv.z*enc_U[(k+2)*H3+j];
        acc += hv.w*enc_U[(k+3)*H3+j];
      }
      hs[j] = acc;
    }
    __syncthreads();
    if (j < H) {
      int row = b*TF + t;
      float xz = xs_all[row*H3 + j];
      float xr = xs_all[row*H3 + 100 + j];
      float xh = xs_all[row*H3 + 200 + j];
      float z = 1.f/(1.f+expf(-(xz + hs[j])));
      float r = 1.f/(1.f+expf(-(xr + hs[100+j])));
      float cand = tanhf(xh + r*hs[200+j]);
      float hn = z*h[j] + (1.f-z)*cand;
      h[j] = hn;                            // safe: h consumed before first sync of this iter
      enc_T[j*ROWS + row] = hn;
    }
    __syncthreads();
  }
  if (j < H) h_state[b*H + j] = h[j];
}

// ---------------- initial attention vectors hW = h@att_W1_top, q = h@att_W2 ----
__global__ __launch_bounds__(256) void k_init_att(const float* h_state, const float* att_W1,
        const float* att_W2, float* hW, float* q) {
  int b = blockIdx.x, c = threadIdx.x;
  __shared__ __align__(16) float h[104];
  if (c < H) h[c] = h_state[b*H + c];
  __syncthreads();
  if (c < H2) {
    float a1 = 0.f, a2 = 0.f;
    const float4* h4 = (const float4*)h;
    #pragma unroll
    for (int k4 = 0; k4 < 25; ++k4) {
      float4 hv = h4[k4];
      int k = k4*4;
      a1 += hv.x*att_W1[(k+0)*H2+c] + hv.y*att_W1[(k+1)*H2+c] + hv.z*att_W1[(k+2)*H2+c] + hv.w*att_W1[(k+3)*H2+c];
      a2 += hv.x*att_W2[(k+0)*H2+c] + hv.y*att_W2[(k+1)*H2+c] + hv.z*att_W2[(k+2)*H2+c] + hv.w*att_W2[(k+3)*H2+c];
    }
    hW[b*H2 + c] = a1;
    q[b*H2 + c]  = a2;
  }
}

// ---------------- decoder big GEMM per step: enc[4096,100] @ W_T^T, lane = t ----
// cols 0..199: score partials (tanh(hW+x)*q summed);  cols 200..455: Y_T (gate pre-activation)
__global__ __launch_bounds__(256) void k_A(const float* enc_T, const float* W_T,
        const float* hW, const float* q, float* sc_part, float* Y_T) {
  int g = blockIdx.x, b = blockIdx.y;
  int w = threadIdx.x >> 6, t = threadIdx.x & 63;
  int row = b*TF + t;
  float e[H];
  #pragma unroll
  for (int k = 0; k < H; ++k) e[k] = enc_T[k*ROWS + row];   // coalesced per k
  float sp = 0.f;
  int cbase = g*64 + w*16;
  for (int i = 0; i < 16; ++i) {
    int c = cbase + i;
    if (c >= NCOLS) break;                   // wave-uniform
    int cu = __builtin_amdgcn_readfirstlane(c);
    const float* wr = W_T + cu*100;
    float acc = 0.f;
    #pragma unroll
    for (int k = 0; k < H; ++k) acc += e[k]*wr[k];           // wr[k] wave-uniform -> scalar
    if (cu < H2) {
      sp += tanhf(hW[b*H2 + cu] + acc) * q[b*H2 + cu];
    } else {
      Y_T[(cu-200)*ROWS + row] = acc;        // coalesced over t
    }
  }
  __shared__ float red[4][64];
  red[w][t] = sp;
  __syncthreads();
  if (w == 0) {
    float s = red[0][t] + red[1][t] + red[2][t] + red[3][t];
    sc_part[(g*B + b)*64 + t] = s;           // always written (0 if no score cols)
  }
}

// ---------------- decoder per-batch sequential part ----
__global__ __launch_bounds__(256) void k_B(int s, const float* sc_part, float* enc_T,
        const float* dec_W, const float* dec_U, const float* dec_b,
        const float* sp1_W, const float* sp1_b, const float* att_W1, const float* att_W2,
        const float* v, const float* c2p, const float* Y_T,
        float* h_state, float* hW, float* q, float* dec_out) {
  int b = blockIdx.x, tid = threadIdx.x;
  int w = tid >> 6, lt = tid & 63;
  __shared__ __align__(16) float alpha[64];
  __shared__ __align__(16) float rd[104];
  __shared__ __align__(16) float h[104];
  __shared__ __align__(16) float hnew[104];
  __shared__ __align__(16) float xs[304];
  __shared__ __align__(16) float hs[304];
  __shared__ __align__(16) float cc[256];
  __shared__ float red[4][64];
  __shared__ float gg[64];

  if (tid >= 64 && tid < 164) h[tid-64] = h_state[b*H + (tid-64)];
  if (tid < 64) {
    float sc = 0.f;
    #pragma unroll
    for (int gi = 0; gi < 8; ++gi) sc += sc_part[(gi*B + b)*64 + tid];
    float m = sc;
    #pragma unroll
    for (int mask = 32; mask >= 1; mask >>= 1) m = fmaxf(m, __shfl_xor(m, mask));
    float ex = expf(sc - m);
    float ssum = ex;
    #pragma unroll
    for (int mask = 32; mask >= 1; mask >>= 1) ssum += __shfl_xor(ssum, mask);
    alpha[tid] = ex / ssum;
  }
  __syncthreads();
  if (tid < H) {                              // attentive read
    float r = 0.f;
    for (int t = 0; t < TF; ++t) r += alpha[t] * enc_T[tid*ROWS + b*TF + t];
    rd[tid] = r;
  }
  __syncthreads();
  for (int j = tid; j < H3; j += 256) {       // GRU matmuls
    float ax = dec_b[j], ah = dec_b[H3 + j];
    const float4* r4 = (const float4*)rd;
    const float4* h4 = (const float4*)h;
    #pragma unroll
    for (int k4 = 0; k4 < 25; ++k4) {
      float4 rv = r4[k4], hv = h4[k4];
      int k = k4*4;
      ax += rv.x*dec_W[(k+0)*H3+j] + rv.y*dec_W[(k+1)*H3+j] + rv.z*dec_W[(k+2)*H3+j] + rv.w*dec_W[(k+3)*H3+j];
      ah += hv.x*dec_U[(k+0)*H3+j] + hv.y*dec_U[(k+1)*H3+j] + hv.z*dec_U[(k+2)*H3+j] + hv.w*dec_U[(k+3)*H3+j];
    }
    xs[j] = ax; hs[j] = ah;
  }
  __syncthreads();
  if (tid < H) {
    float z = 1.f/(1.f+expf(-(xs[tid] + hs[tid])));
    float r = 1.f/(1.f+expf(-(xs[100+tid] + hs[100+tid])));
    float cand = tanhf(xs[200+tid] + r*hs[200+tid]);
    float hn = z*h[tid] + (1.f-z)*cand;
    hnew[tid] = hn;
    h_state[b*H + tid] = hn;
    dec_out[(b*TE + s)*H + tid] = hn;
  }
  __syncthreads();
  {                                           // c = hnew@sp1a + rd@sp1b + sp1_b
    int j = tid;
    float a = sp1_b[j];
    const float4* n4 = (const float4*)hnew;
    const float4* r4 = (const float4*)rd;
    #pragma unroll
    for (int k4 = 0; k4 < 25; ++k4) {
      float4 nv = n4[k4], rv = r4[k4];
      int k = k4*4;
      a += nv.x*sp1_W[(k+0)*SP+j] + nv.y*sp1_W[(k+1)*SP+j] + nv.z*sp1_W[(k+2)*SP+j] + nv.w*sp1_W[(k+3)*SP+j];
      a += rv.x*sp1_W[(100+k+0)*SP+j] + rv.y*sp1_W[(100+k+1)*SP+j] + rv.z*sp1_W[(100+k+2)*SP+j] + rv.w*sp1_W[(100+k+3)*SP+j];
    }
    cc[j] = a;
  }
  if (tid < H2) {                             // next-step hW, q
    float a1 = 0.f, a2 = 0.f;
    const float4* n4 = (const float4*)hnew;
    #pragma unroll
    for (int k4 = 0; k4 < 25; ++k4) {
      float4 nv = n4[k4];
      int k = k4*4;
      a1 += nv.x*att_W1[(k+0)*H2+tid] + nv.y*att_W1[(k+1)*H2+tid] + nv.z*att_W1[(k+2)*H2+tid] + nv.w*att_W1[(k+3)*H2+tid];
      a2 += nv.x*att_W2[(k+0)*H2+tid] + nv.y*att_W2[(k+1)*H2+tid] + nv.z*att_W2[(k+2)*H2+tid] + nv.w*att_W2[(k+3)*H2+tid];
    }
    hW[b*H2 + tid] = a1;
    q[b*H2 + tid]  = a2;
  }
  __syncthreads();
  {                                           // gate dot (v-trick)
    float gp = 0.f;
    int jbase = w*64;
    #pragma unroll 8
    for (int jj = 0; jj < 64; ++jj) {
      int j = jbase + jj;
      float y = cc[j] + Y_T[j*ROWS + b*TF + lt];
      gp += fmaxf(y, 0.f) * v[j];
    }
    red[w][lt] = gp;
  }
  __syncthreads();
  if (w == 0) {
    float gd = red[0][lt] + red[1][lt] + red[2][lt] + red[3][lt] + *c2p;
    gg[lt] = 1.f/(1.f+expf(-gd));
  }
  __syncthreads();
  for (int idx = tid; idx < H*TF; idx += 256) {  // enc update
    int k = idx >> 6, t = idx & 63;
    int a = k*ROWS + b*TF + t;
    float g = gg[t];
    enc_T[a] = g*enc_T[a] + (1.f-g)*rd[k];
  }
}

// ---------------- ff1: hid = relu(dec_out @ ff1_W + b) ----
__global__ __launch_bounds__(128) void k_ff1(const float* dec_out, const float* ff1_W,
        const float* ff1_b, float* hid) {
  int row = blockIdx.x, j = threadIdx.x;
  __shared__ __align__(16) float a[104];
  if (j < H) a[j] = dec_out[row*H + j];
  __syncthreads();
  if (j < H) {
    float acc = ff1_b[j];
    const float4* a4 = (const float4*)a;
    #pragma unroll
    for (int k4 = 0; k4 < 25; ++k4) {
      float4 av = a4[k4];
      int k = k4*4;
      acc += av.x*ff1_W[(k+0)*H+j] + av.y*ff1_W[(k+1)*H+j] + av.z*ff1_W[(k+2)*H+j] + av.w*ff1_W[(k+3)*H+j];
    }
    hid[row*H + j] = fmaxf(acc, 0.f);
  }
}

// ---------------- logits GEMM: [2048,100] x [100,20000] -> d_out ----
#define KC 20
__global__ __launch_bounds__(256) void k_logits(const float* hid, const float* ff2_W,
        const float* ff2_b, float* out) {
  int bx = blockIdx.x, by = blockIdx.y;
  int tid = threadIdx.x;
  int tx = tid & 15, ty = tid >> 4;
  __shared__ __align__(16) float At[100*132];
  __shared__ __align__(16) float Wt[KC*132];
  int r0 = by*128;
  int c0 = bx*128;
  for (int i = tid; i < 128*100; i += 256) {
    int r = i & 127, k = i >> 7;
    At[k*132 + r] = hid[(r0+r)*H + k];
  }
  float acc[8][8];
  #pragma unroll
  for (int i = 0; i < 8; ++i) {
    #pragma unroll
    for (int j = 0; j < 8; ++j) acc[i][j] = 0.f;
  }
  for (int kc = 0; kc < 100; kc += KC) {
    __syncthreads();
    for (int i = tid; i < 128*KC; i += 256) {
      int cidx = i & 127, kk = i >> 7;
      int gc = c0 + cidx;
      Wt[kk*132 + cidx] = (gc < EV) ? ff2_W[(size_t)(kc+kk)*EV + gc] : 0.f;
    }
    __syncthreads();
    #pragma unroll
    for (int kk = 0; kk < KC; ++kk) {
      const float* Ar = At + (kc+kk)*132;
      const float* Wr = Wt + kk*132;
      float4 a0 = *(const float4*)(Ar + ty*4);
      float4 a1 = *(const float4*)(Ar + 64 + ty*4);
      float4 w0 = *(const float4*)(Wr + tx*4);
      float4 w1 = *(const float4*)(Wr + 64 + tx*4);
      float av[8] = {a0.x,a0.y,a0.z,a0.w,a1.x,a1.y,a1.z,a1.w};
      float wv[8] = {w0.x,w0.y,w0.z,w0.w,w1.x,w1.y,w1.z,w1.w};
      #pragma unroll
      for (int i = 0; i < 8; ++i) {
        #pragma unroll
        for (int j = 0; j < 8; ++j) acc[i][j] += av[i]*wv[j];
      }
    }
  }
  #pragma unroll
  for (int i = 0; i < 8; ++i) {
    int r = r0 + ty*4 + (i < 4 ? i : 60 + i);
    float* orow = out + (size_t)r*EV;
    int ca = c0 + tx*4;
    if (ca < EV) {
      float4 bb = *(const float4*)(ff2_b + ca);
      float4 val = {acc[i][0]+bb.x, acc[i][1]+bb.y, acc[i][2]+bb.z, acc[i][3]+bb.w};
      *(float4*)(orow + ca) = val;
    }
    int cb = c0 + 64 + tx*4;
    if (cb < EV) {
      float4 bb = *(const float4*)(ff2_b + cb);
      float4 val = {acc[i][4]+bb.x, acc[i][5]+bb.y, acc[i][6]+bb.z, acc[i][7]+bb.w};
      *(float4*)(orow + cb) = val;
    }
  }
}

// ---------------- in-place row softmax on d_out ----
__global__ __launch_bounds__(256) void k_softmax(float* out) {
  int row = blockIdx.x, tid = threadIdx.x;
  float* p = out + (size_t)row*EV;
  float m = -1e30f, ssum = 0.f;
  for (int j = tid; j < EV; j += 256) {
    float x = p[j];
    if (x > m) { ssum = ssum*expf(m - x) + 1.f; m = x; }
    else ssum += expf(x - m);
  }
  __shared__ float sm[256], ss[256];
  sm[tid] = m; ss[tid] = ssum;
  __syncthreads();
  for (int st = 128; st >= 1; st >>= 1) {
    if (tid < st) {
      float m2 = sm[tid+st], s2 = ss[tid+st];
      float M = fmaxf(sm[tid], m2);
      ss[tid] = ss[tid]*expf(sm[tid]-M) + s2*expf(m2-M);
      sm[tid] = M;
    }
    __syncthreads();
  }
  float M = sm[0];
  float inv = 1.f/ss[0];
  for (int j = tid; j < EV; j += 256) {
    p[j] = expf(p[j] - M) * inv;
  }
}

extern "C" void kernel_launch(void* const* d_in, const int* in_sizes, int n_in,
                              void* d_out, int out_size, void* d_ws, size_t ws_size,
                              hipStream_t stream) {
  (void)in_sizes; (void)n_in; (void)out_size;
  const int*   enc_in  = (const int*)d_in[0];
  const float* femb    = (const float*)d_in[2];
  const float* enc_W   = (const float*)d_in[4];
  const float* enc_U   = (const float*)d_in[5];
  const float* enc_b   = (const float*)d_in[6];
  const float* dec_W   = (const float*)d_in[7];
  const float* dec_U   = (const float*)d_in[8];
  const float* dec_b   = (const float*)d_in[9];
  const float* att_W1  = (const float*)d_in[10];
  const float* att_W2  = (const float*)d_in[11];
  const float* sp1_W   = (const float*)d_in[12];
  const float* sp1_b   = (const float*)d_in[13];
  const float* sp2_W   = (const float*)d_in[14];
  const float* sp2_b   = (const float*)d_in[15];
  const float* ff1_W   = (const float*)d_in[16];
  const float* ff1_b   = (const float*)d_in[17];
  const float* ff2_W   = (const float*)d_in[18];
  const float* ff2_b   = (const float*)d_in[19];
  float* out = (float*)d_out;
  float* ws  = (float*)d_ws;

  float* enc_T  = ws + 0;          // 100*4096  = 409600
  float* W_T    = ws + 409600;     // 456*100   = 45600
  float* hW     = ws + 455200;     // 64*200    = 12800
  float* qbuf   = ws + 468000;     // 64*200    = 12800
  float* scp    = ws + 480800;     // 8*64*64   = 32768
  float* Y_T    = ws + 513568;     // 256*4096  = 1048576
  float* h_st   = ws + 1562144;    // 64*100    = 6400
  float* dec_o  = ws + 1568544;    // 2048*100  = 204800
  float* hid    = ws + 1773344;    // 2048*100  = 204800
  float* xs_all = ws + 1978144;    // 4096*300  = 1228800
  float* vbuf   = ws + 3206944;    // 256
  float* c2buf  = ws + 3207200;    // 1
  if (ws_size < (size_t)3207232*4) return;   // need ~12.8 MB

  k_setup<<<184, 256, 0, stream>>>(att_W1, sp1_W, sp2_W, sp2_b, W_T, vbuf, c2buf);
  k_embed<<<4096, 320, 0, stream>>>(enc_in, femb, enc_W, enc_b, xs_all);
  k_enc<<<64, 320, 0, stream>>>(enc_U, enc_b, xs_all, enc_T, h_st);
  k_init_att<<<64, 256, 0, stream>>>(h_st, att_W1, att_W2, hW, qbuf);
  for (int s = 0; s < TE; ++s) {
    k_A<<<dim3(8, 64), 256, 0, stream>>>(enc_T, W_T, hW, qbuf, scp, Y_T);
    k_B<<<64, 256, 0, stream>>>(s, scp, enc_T, dec_W, dec_U, dec_b, sp1_W, sp1_b,
                                att_W1, att_W2, vbuf, c2buf, Y_T, h_st, hW, qbuf, dec_o);
  }
  k_ff1<<<2048, 128, 0, stream>>>(dec_o, ff1_W, ff1_b, hid);
  k_logits<<<dim3(157, 16), 256, 0, stream>>>(hid, ff2_W, ff2_b, out);
  k_softmax<<<2048, 256, 0, stream>>>(out);
}

// Round 2
// 2443.717 us; speedup vs baseline: 1.3806x; 1.3806x over previous
//
#include <hip/hip_runtime.h>
#include <math.h>

#define B 64
#define TF 64
#define TE 32
#define E_DIM 40
#define H 100
#define H2 200
#define H3 300
#define SP 256
#define EV 20000
#define ROWS (B*TF)        // 4096
#define NCOLS 456          // 200 score cols + 256 Y cols

// ---------------- setup: W_T (concat of att_W1 bottom + sp1_W enc part, transposed), v, c2 ----
__global__ __launch_bounds__(256) void k_setup(const float* att_W1, const float* sp1_W,
        const float* sp2_W, const float* sp2_b, float* W_T, float* v, float* c2) {
  int bid = blockIdx.x;
  if (bid < 182) {
    int idx = bid*256 + threadIdx.x;
    if (idx < NCOLS*H) {
      int c = idx / 100, k = idx - c*100;
      float val;
      if (c < H2) val = att_W1[(100+k)*H2 + c];
      else        val = sp1_W[(200+k)*SP + (c-200)];
      W_T[idx] = val;                       // W_T[c*100+k]
    }
  } else if (bid == 182) {
    int k = threadIdx.x;                    // 0..255
    float s = 0.f;
    for (int j = 0; j < SP; ++j) s += sp2_W[k*SP + j];
    v[k] = s * (1.f/256.f);
  } else {
    if (threadIdx.x == 0) {
      float s = 0.f;
      for (int j = 0; j < SP; ++j) s += sp2_b[j];
      *c2 = s * (1.f/256.f);
    }
  }
}

// ---------------- encoder xs = embed @ enc_W + enc_b[0] (parallel over all (b,t)) ----
__global__ __launch_bounds__(320) void k_embed(const int* enc_in, const float* femb,
        const float* enc_W, const float* enc_b, float* xs_all) {
  int row = blockIdx.x;
  int j = threadIdx.x;
  __shared__ __align__(16) float emb[E_DIM];
  int tok = enc_in[row];
  if (j < E_DIM) emb[j] = femb[tok*E_DIM + j];
  __syncthreads();
  if (j < H3) {
    float acc = enc_b[j];                   // b[0]
    #pragma unroll
    for (int k = 0; k < E_DIM; ++k) acc += emb[k]*enc_W[k*H3 + j];
    xs_all[row*H3 + j] = acc;
  }
}

// ---------------- encoder GRU recurrence: one block per batch, U register-resident ----
// 192 threads: threads 0..149 each own 2 columns of U (cols 2t, 2t+1) held in VGPRs.
__global__ __launch_bounds__(192) void k_enc(const float* __restrict__ enc_U,
        const float* __restrict__ enc_b, const float* __restrict__ xs_all,
        float* __restrict__ enc_T, float* __restrict__ h_state) {
  int b = blockIdx.x, t = threadIdx.x;
  __shared__ __align__(16) float hsh[104];
  __shared__ __align__(16) float hs[304];

  float2 Ur[100];
  float2 bias = {0.f, 0.f};
  if (t < 150) {
    const float* base = enc_U + 2*t;
    #pragma unroll
    for (int k = 0; k < 100; ++k) Ur[k] = *(const float2*)(base + k*H3);
    bias = *(const float2*)(enc_b + H3 + 2*t);
  }
  if (t < H) hsh[t] = 0.f;
  __syncthreads();

  #pragma unroll 1
  for (int step = 0; step < TF; ++step) {
    int row = b*TF + step;
    float xz = 0.f, xr = 0.f, xh = 0.f;
    if (t < H) {                           // prefetch x-part (overlaps matvec)
      xz = xs_all[row*H3 + t];
      xr = xs_all[row*H3 + 100 + t];
      xh = xs_all[row*H3 + 200 + t];
    }
    if (t < 150) {                         // hs = h @ U + b1 (2 cols/thread)
      float a0 = bias.x, a1 = bias.y;
      const float4* h4 = (const float4*)hsh;
      #pragma unroll
      for (int k4 = 0; k4 < 25; ++k4) {
        float4 hv = h4[k4];
        a0 += hv.x*Ur[k4*4+0].x + hv.y*Ur[k4*4+1].x + hv.z*Ur[k4*4+2].x + hv.w*Ur[k4*4+3].x;
        a1 += hv.x*Ur[k4*4+0].y + hv.y*Ur[k4*4+1].y + hv.z*Ur[k4*4+2].y + hv.w*Ur[k4*4+3].y;
      }
      hs[2*t]   = a0;
      hs[2*t+1] = a1;
    }
    __syncthreads();
    if (t < H) {
      float z = 1.f/(1.f+expf(-(xz + hs[t])));
      float r = 1.f/(1.f+expf(-(xr + hs[100+t])));
      float cand = tanhf(xh + r*hs[200+t]);
      float hn = z*hsh[t] + (1.f-z)*cand;
      hsh[t] = hn;
      enc_T[t*ROWS + row] = hn;
    }
    __syncthreads();
  }
  if (t < H) h_state[b*H + t] = hsh[t];
}

// ---------------- initial attention vectors hW = h@att_W1_top, q = h@att_W2 ----
__global__ __launch_bounds__(256) void k_init_att(const float* h_state, const float* att_W1,
        const float* att_W2, float* hW, float* q) {
  int b = blockIdx.x, c = threadIdx.x;
  __shared__ __align__(16) float h[104];
  if (c < H) h[c] = h_state[b*H + c];
  __syncthreads();
  if (c < H2) {
    float a1 = 0.f, a2 = 0.f;
    const float4* h4 = (const float4*)h;
    #pragma unroll
    for (int k4 = 0; k4 < 25; ++k4) {
      float4 hv = h4[k4];
      int k = k4*4;
      a1 += hv.x*att_W1[(k+0)*H2+c] + hv.y*att_W1[(k+1)*H2+c] + hv.z*att_W1[(k+2)*H2+c] + hv.w*att_W1[(k+3)*H2+c];
      a2 += hv.x*att_W2[(k+0)*H2+c] + hv.y*att_W2[(k+1)*H2+c] + hv.z*att_W2[(k+2)*H2+c] + hv.w*att_W2[(k+3)*H2+c];
    }
    hW[b*H2 + c] = a1;
    q[b*H2 + c]  = a2;
  }
}

// ---------------- decoder big GEMM per step: enc[4096,100] @ W_T^T, lane = t ----
__global__ __launch_bounds__(256) void k_A(const float* enc_T, const float* W_T,
        const float* hW, const float* q, float* sc_part, float* Y_T) {
  int g = blockIdx.x, b = blockIdx.y;
  int w = threadIdx.x >> 6, t = threadIdx.x & 63;
  int row = b*TF + t;
  float e[H];
  #pragma unroll
  for (int k = 0; k < H; ++k) e[k] = enc_T[k*ROWS + row];   // coalesced per k
  float sp = 0.f;
  int cbase = g*64 + w*16;
  for (int i = 0; i < 16; ++i) {
    int c = cbase + i;
    if (c >= NCOLS) break;                   // wave-uniform
    int cu = __builtin_amdgcn_readfirstlane(c);
    const float* wr = W_T + cu*100;
    float acc = 0.f;
    #pragma unroll
    for (int k = 0; k < H; ++k) acc += e[k]*wr[k];           // wr[k] wave-uniform -> scalar
    if (cu < H2) {
      sp += tanhf(hW[b*H2 + cu] + acc) * q[b*H2 + cu];
    } else {
      Y_T[(cu-200)*ROWS + row] = acc;        // coalesced over t
    }
  }
  __shared__ float red[4][64];
  red[w][t] = sp;
  __syncthreads();
  if (w == 0) {
    float s = red[0][t] + red[1][t] + red[2][t] + red[3][t];
    sc_part[(g*B + b)*64 + t] = s;
  }
}

// ---------------- decoder per-batch sequential part: 640 threads (10 waves) ----
__global__ __launch_bounds__(640) void k_B(int s, const float* __restrict__ sc_part,
        float* __restrict__ enc_T,
        const float* __restrict__ dec_W, const float* __restrict__ dec_U,
        const float* __restrict__ dec_b,
        const float* __restrict__ sp1_W, const float* __restrict__ sp1_b,
        const float* __restrict__ att_W1, const float* __restrict__ att_W2,
        const float* __restrict__ v, const float* __restrict__ c2p,
        const float* __restrict__ Y_T,
        float* __restrict__ h_state, float* __restrict__ hW, float* __restrict__ q,
        float* __restrict__ dec_out) {
  int b = blockIdx.x, tid = threadIdx.x;
  int w = tid >> 6, lane = tid & 63;
  __shared__ __align__(16) float alpha[64];
  __shared__ __align__(16) float rd[104];
  __shared__ __align__(16) float h[104];
  __shared__ __align__(16) float hnew[104];
  __shared__ __align__(16) float xs[304];
  __shared__ __align__(16) float hs[304];
  __shared__ __align__(16) float ccp[2][256];
  __shared__ float red[8][64];
  __shared__ float gg[64];

  // phase 0/1: load h; softmax of scores (wave 0)
  if (tid >= 64 && tid < 164) h[tid-64] = h_state[b*H + (tid-64)];
  if (tid < 64) {
    float sc = 0.f;
    #pragma unroll
    for (int gi = 0; gi < 8; ++gi) sc += sc_part[(gi*B + b)*64 + tid];
    float m = sc;
    #pragma unroll
    for (int mask = 32; mask >= 1; mask >>= 1) m = fmaxf(m, __shfl_xor(m, mask));
    float ex = expf(sc - m);
    float ssum = ex;
    #pragma unroll
    for (int mask = 32; mask >= 1; mask >>= 1) ssum += __shfl_xor(ssum, mask);
    alpha[tid] = ex / ssum;
  }
  __syncthreads();

  // phase 2: attentive read — wave w computes j = w*10..w*10+9, lane-coalesced + shuffle reduce
  {
    float al = alpha[lane];
    #pragma unroll
    for (int i = 0; i < 10; ++i) {
      int j = w*10 + i;
      if (j < H) {
        float vsum = al * enc_T[j*ROWS + b*TF + lane];
        #pragma unroll
        for (int mask = 32; mask >= 1; mask >>= 1) vsum += __shfl_xor(vsum, mask);
        if (lane == 0) rd[j] = vsum;
      }
    }
  }
  __syncthreads();

  // phase 3: GRU matvecs in parallel groups: xs (threads 0..299), hs (threads 320..619)
  if (tid < H3) {
    int j = tid;
    float ax = dec_b[j];
    const float4* r4 = (const float4*)rd;
    #pragma unroll
    for (int k4 = 0; k4 < 25; ++k4) {
      float4 rv = r4[k4];
      int k = k4*4;
      ax += rv.x*dec_W[(k+0)*H3+j] + rv.y*dec_W[(k+1)*H3+j] + rv.z*dec_W[(k+2)*H3+j] + rv.w*dec_W[(k+3)*H3+j];
    }
    xs[j] = ax;
  } else if (tid >= 320 && tid < 320 + H3) {
    int j = tid - 320;
    float ah = dec_b[H3 + j];
    const float4* h4 = (const float4*)h;
    #pragma unroll
    for (int k4 = 0; k4 < 25; ++k4) {
      float4 hv = h4[k4];
      int k = k4*4;
      ah += hv.x*dec_U[(k+0)*H3+j] + hv.y*dec_U[(k+1)*H3+j] + hv.z*dec_U[(k+2)*H3+j] + hv.w*dec_U[(k+3)*H3+j];
    }
    hs[j] = ah;
  }
  __syncthreads();

  // phase 4: GRU gate update
  if (tid < H) {
    float z = 1.f/(1.f+expf(-(xs[tid] + hs[tid])));
    float r = 1.f/(1.f+expf(-(xs[100+tid] + hs[100+tid])));
    float cand = tanhf(xs[200+tid] + r*hs[200+tid]);
    float hn = z*h[tid] + (1.f-z)*cand;
    hnew[tid] = hn;
    h_state[b*H + tid] = hn;
    dec_out[(b*TE + s)*H + tid] = hn;
  }
  __syncthreads();

  // phase 5: cc partials (k-split over 512 threads): cc = hnew@sp1W[0:100] + rd@sp1W[100:200] + b
  if (tid < 512) {
    int jj = tid & 255, kh = tid >> 8;
    const float* inv = kh ? rd : hnew;
    const float* wbase = sp1_W + kh*100*SP;
    float a = kh ? 0.f : sp1_b[jj];
    const float4* i4 = (const float4*)inv;
    #pragma unroll
    for (int k4 = 0; k4 < 25; ++k4) {
      float4 iv = i4[k4];
      int k = k4*4;
      a += iv.x*wbase[(k+0)*SP+jj] + iv.y*wbase[(k+1)*SP+jj] + iv.z*wbase[(k+2)*SP+jj] + iv.w*wbase[(k+3)*SP+jj];
    }
    ccp[kh][jj] = a;
  }
  __syncthreads();

  // phase 6: gate dot (v-trick), 8 waves x 32 j each
  if (w < 8) {
    float gp = 0.f;
    int jbase = w*32;
    #pragma unroll 8
    for (int jj = 0; jj < 32; ++jj) {
      int j = jbase + jj;
      float y = ccp[0][j] + ccp[1][j] + Y_T[j*ROWS + b*TF + lane];
      gp += fmaxf(y, 0.f) * v[j];
    }
    red[w][lane] = gp;
  }
  __syncthreads();
  if (w == 0) {
    float gd = red[0][lane] + red[1][lane] + red[2][lane] + red[3][lane]
             + red[4][lane] + red[5][lane] + red[6][lane] + red[7][lane] + *c2p;
    gg[lane] = 1.f/(1.f+expf(-gd));
  }
  __syncthreads();

  // phase 7 (parallel): waves 6..9 -> enc update; waves 0..5 -> next-step hW/q
  if (tid >= 384) {
    int t0 = tid - 384;                       // 256 threads
    #pragma unroll
    for (int i = 0; i < 25; ++i) {
      int idx = i*256 + t0;
      int k = idx >> 6, t = idx & 63;
      int a = k*ROWS + b*TF + t;
      float g = gg[t];
      enc_T[a] = g*enc_T[a] + (1.f-g)*rd[k];
    }
  } else {
    for (int c = tid; c < 400; c += 384) {
      const float* Wm = (c < H2) ? att_W1 : att_W2;
      int col = (c < H2) ? c : c - H2;
      float a1 = 0.f;
      const float4* n4 = (const float4*)hnew;
      #pragma unroll
      for (int k4 = 0; k4 < 25; ++k4) {
        float4 nv = n4[k4];
        int k = k4*4;
        a1 += nv.x*Wm[(k+0)*H2+col] + nv.y*Wm[(k+1)*H2+col] + nv.z*Wm[(k+2)*H2+col] + nv.w*Wm[(k+3)*H2+col];
      }
      if (c < H2) hW[b*H2 + col] = a1;
      else        q[b*H2 + col]  = a1;
    }
  }
}

// ---------------- ff1: hid = relu(dec_out @ ff1_W + b) ----
__global__ __launch_bounds__(128) void k_ff1(const float* dec_out, const float* ff1_W,
        const float* ff1_b, float* hid) {
  int row = blockIdx.x, j = threadIdx.x;
  __shared__ __align__(16) float a[104];
  if (j < H) a[j] = dec_out[row*H + j];
  __syncthreads();
  if (j < H) {
    float acc = ff1_b[j];
    const float4* a4 = (const float4*)a;
    #pragma unroll
    for (int k4 = 0; k4 < 25; ++k4) {
      float4 av = a4[k4];
      int k = k4*4;
      acc += av.x*ff1_W[(k+0)*H+j] + av.y*ff1_W[(k+1)*H+j] + av.z*ff1_W[(k+2)*H+j] + av.w*ff1_W[(k+3)*H+j];
    }
    hid[row*H + j] = fmaxf(acc, 0.f);
  }
}

// ---------------- logits GEMM: [2048,100] x [100,20000] -> d_out ----
#define KC 20
__global__ __launch_bounds__(256) void k_logits(const float* hid, const float* ff2_W,
        const float* ff2_b, float* out) {
  int bx = blockIdx.x, by = blockIdx.y;
  int tid = threadIdx.x;
  int tx = tid & 15, ty = tid >> 4;
  __shared__ __align__(16) float At[100*132];
  __shared__ __align__(16) float Wt[KC*132];
  int r0 = by*128;
  int c0 = bx*128;
  for (int i = tid; i < 128*100; i += 256) {
    int r = i & 127, k = i >> 7;
    At[k*132 + r] = hid[(r0+r)*H + k];
  }
  float acc[8][8];
  #pragma unroll
  for (int i = 0; i < 8; ++i) {
    #pragma unroll
    for (int j = 0; j < 8; ++j) acc[i][j] = 0.f;
  }
  for (int kc = 0; kc < 100; kc += KC) {
    __syncthreads();
    for (int i = tid; i < 128*KC; i += 256) {
      int cidx = i & 127, kk = i >> 7;
      int gc = c0 + cidx;
      Wt[kk*132 + cidx] = (gc < EV) ? ff2_W[(size_t)(kc+kk)*EV + gc] : 0.f;
    }
    __syncthreads();
    #pragma unroll
    for (int kk = 0; kk < KC; ++kk) {
      const float* Ar = At + (kc+kk)*132;
      const float* Wr = Wt + kk*132;
      float4 a0 = *(const float4*)(Ar + ty*4);
      float4 a1 = *(const float4*)(Ar + 64 + ty*4);
      float4 w0 = *(const float4*)(Wr + tx*4);
      float4 w1 = *(const float4*)(Wr + 64 + tx*4);
      float av[8] = {a0.x,a0.y,a0.z,a0.w,a1.x,a1.y,a1.z,a1.w};
      float wv[8] = {w0.x,w0.y,w0.z,w0.w,w1.x,w1.y,w1.z,w1.w};
      #pragma unroll
      for (int i = 0; i < 8; ++i) {
        #pragma unroll
        for (int j = 0; j < 8; ++j) acc[i][j] += av[i]*wv[j];
      }
    }
  }
  #pragma unroll
  for (int i = 0; i < 8; ++i) {
    int r = r0 + ty*4 + (i < 4 ? i : 60 + i);
    float* orow = out + (size_t)r*EV;
    int ca = c0 + tx*4;
    if (ca < EV) {
      float4 bb = *(const float4*)(ff2_b + ca);
      float4 val = {acc[i][0]+bb.x, acc[i][1]+bb.y, acc[i][2]+bb.z, acc[i][3]+bb.w};
      *(float4*)(orow + ca) = val;
    }
    int cb = c0 + 64 + tx*4;
    if (cb < EV) {
      float4 bb = *(const float4*)(ff2_b + cb);
      float4 val = {acc[i][4]+bb.x, acc[i][5]+bb.y, acc[i][6]+bb.z, acc[i][7]+bb.w};
      *(float4*)(orow + cb) = val;
    }
  }
}

// ---------------- in-place row softmax on d_out ----
__global__ __launch_bounds__(256) void k_softmax(float* out) {
  int row = blockIdx.x, tid = threadIdx.x;
  float* p = out + (size_t)row*EV;
  float m = -1e30f, ssum = 0.f;
  for (int j = tid; j < EV; j += 256) {
    float x = p[j];
    if (x > m) { ssum = ssum*expf(m - x) + 1.f; m = x; }
    else ssum += expf(x - m);
  }
  __shared__ float sm[256], ss[256];
  sm[tid] = m; ss[tid] = ssum;
  __syncthreads();
  for (int st = 128; st >= 1; st >>= 1) {
    if (tid < st) {
      float m2 = sm[tid+st], s2 = ss[tid+st];
      float M = fmaxf(sm[tid], m2);
      ss[tid] = ss[tid]*expf(sm[tid]-M) + s2*expf(m2-M);
      sm[tid] = M;
    }
    __syncthreads();
  }
  float M = sm[0];
  float inv = 1.f/ss[0];
  for (int j = tid; j < EV; j += 256) {
    p[j] = expf(p[j] - M) * inv;
  }
}

extern "C" void kernel_launch(void* const* d_in, const int* in_sizes, int n_in,
                              void* d_out, int out_size, void* d_ws, size_t ws_size,
                              hipStream_t stream) {
  (void)in_sizes; (void)n_in; (void)out_size;
  const int*   enc_in  = (const int*)d_in[0];
  const float* femb    = (const float*)d_in[2];
  const float* enc_W   = (const float*)d_in[4];
  const float* enc_U   = (const float*)d_in[5];
  const float* enc_b   = (const float*)d_in[6];
  const float* dec_W   = (const float*)d_in[7];
  const float* dec_U   = (const float*)d_in[8];
  const float* dec_b   = (const float*)d_in[9];
  const float* att_W1  = (const float*)d_in[10];
  const float* att_W2  = (const float*)d_in[11];
  const float* sp1_W   = (const float*)d_in[12];
  const float* sp1_b   = (const float*)d_in[13];
  const float* sp2_W   = (const float*)d_in[14];
  const float* sp2_b   = (const float*)d_in[15];
  const float* ff1_W   = (const float*)d_in[16];
  const float* ff1_b   = (const float*)d_in[17];
  const float* ff2_W   = (const float*)d_in[18];
  const float* ff2_b   = (const float*)d_in[19];
  float* out = (float*)d_out;
  float* ws  = (float*)d_ws;

  float* enc_T  = ws + 0;          // 100*4096  = 409600
  float* W_T    = ws + 409600;     // 456*100   = 45600
  float* hW     = ws + 455200;     // 64*200    = 12800
  float* qbuf   = ws + 468000;     // 64*200    = 12800
  float* scp    = ws + 480800;     // 8*64*64   = 32768
  float* Y_T    = ws + 513568;     // 256*4096  = 1048576
  float* h_st   = ws + 1562144;    // 64*100    = 6400
  float* dec_o  = ws + 1568544;    // 2048*100  = 204800
  float* hid    = ws + 1773344;    // 2048*100  = 204800
  float* xs_all = ws + 1978144;    // 4096*300  = 1228800
  float* vbuf   = ws + 3206944;    // 256
  float* c2buf  = ws + 3207200;    // 1
  if (ws_size < (size_t)3207232*4) return;   // need ~12.8 MB

  k_setup<<<184, 256, 0, stream>>>(att_W1, sp1_W, sp2_W, sp2_b, W_T, vbuf, c2buf);
  k_embed<<<4096, 320, 0, stream>>>(enc_in, femb, enc_W, enc_b, xs_all);
  k_enc<<<64, 192, 0, stream>>>(enc_U, enc_b, xs_all, enc_T, h_st);
  k_init_att<<<64, 256, 0, stream>>>(h_st, att_W1, att_W2, hW, qbuf);
  for (int s = 0; s < TE; ++s) {
    k_A<<<dim3(8, 64), 256, 0, stream>>>(enc_T, W_T, hW, qbuf, scp, Y_T);
    k_B<<<64, 640, 0, stream>>>(s, scp, enc_T, dec_W, dec_U, dec_b, sp1_W, sp1_b,
                                att_W1, att_W2, vbuf, c2buf, Y_T, h_st, hW, qbuf, dec_o);
  }
  k_ff1<<<2048, 128, 0, stream>>>(dec_o, ff1_W, ff1_b, hid);
  k_logits<<<dim3(157, 16), 256, 0, stream>>>(hid, ff2_W, ff2_b, out);
  k_softmax<<<2048, 256, 0, stream>>>(out);
}